// Round 14
// baseline (566.118 us; speedup 1.0000x reference)
//
#include <hip/hip_runtime.h>

typedef _Float16 f16x8 __attribute__((ext_vector_type(8)));
typedef float    f32x4 __attribute__((ext_vector_type(4)));
typedef unsigned short u16;

#define VOC   128000
#define TOPIC 512
#define EMB   1024
#define BATCH 1024
#define ROWB  128   // LDS row = 64 f16 = 128 B (BK=64)

__device__ __forceinline__ int swz(int row, int kbyte) {
    return row * ROWB + (kbyte ^ ((row & 7) << 4));
}
__device__ __forceinline__ int xcd_swz(int bid, int nwg) {
    int x = bid & 7, o = bid >> 3, q = nwg >> 3, r = nwg & 7;
    return (x < r ? x * (q + 1) : r * (q + 1) + (x - r) * q) + o;
}
union H2U { _Float16 h; u16 u; };

#define SBAR() asm volatile("s_barrier" ::: "memory")
#define WVM0() asm volatile("s_waitcnt vmcnt(0)" ::: "memory")
#define WVM2() asm volatile("s_waitcnt vmcnt(2)" ::: "memory")
#define WVM8() asm volatile("s_waitcnt vmcnt(8)" ::: "memory")
#define WLG0() asm volatile("s_waitcnt lgkmcnt(0)" ::: "memory")

#define GLDS(SRC, DST) __builtin_amdgcn_global_load_lds( \
    (const __attribute__((address_space(1))) unsigned int*)(SRC), \
    (__attribute__((address_space(3))) unsigned int*)(DST), 16, 0, 0)

// Fragment reads. Per-buf layout: A rows 0..255 @0 (32KB), B rows 0..255 @32768.
#define RD_AF(BUF, MH) { _Pragma("unroll") \
    for (int m = 0; m < 4; ++m) { _Pragma("unroll") \
    for (int ks = 0; ks < 2; ++ks) \
        af[m*2+ks] = *(const f16x8*)((BUF) + \
            swz(wr*128 + (MH)*64 + m*16 + lr, ks*64 + lk*16)); } }
#define RD_BF(BUF, NH) { _Pragma("unroll") \
    for (int n = 0; n < 2; ++n) { _Pragma("unroll") \
    for (int ks = 0; ks < 2; ++ks) \
        bf[n*2+ks] = *(const f16x8*)((BUF) + 32768 + \
            swz(wc*64 + (NH)*32 + n*16 + lr, ks*64 + lk*16)); } }
#define MM(MH, NH) { __builtin_amdgcn_s_setprio(1); \
    _Pragma("unroll") for (int m = 0; m < 4; ++m) { \
    _Pragma("unroll") for (int n = 0; n < 2; ++n) { \
    _Pragma("unroll") for (int ks = 0; ks < 2; ++ks) \
        acc[(MH)*4+m][(NH)*2+n] = __builtin_amdgcn_mfma_f32_16x16x32_f16( \
            af[m*2+ks], bf[n*2+ks], acc[(MH)*4+m][(NH)*2+n], 0, 0, 0); } } \
    __builtin_amdgcn_s_setprio(0); }

// ---------------------------------------------------------------------------
// K0: betat f32 -> f16
// ---------------------------------------------------------------------------
__global__ void cvt_betat_kernel(const float* __restrict__ betat, u16* __restrict__ bt16) {
    const size_t g = (size_t)blockIdx.x * 256 + threadIdx.x;
    const float4* src = reinterpret_cast<const float4*>(betat) + g * 2;
    float4 a = src[0], b = src[1];
    f16x8 h;
    h[0]=(_Float16)a.x; h[1]=(_Float16)a.y; h[2]=(_Float16)a.z; h[3]=(_Float16)a.w;
    h[4]=(_Float16)b.x; h[5]=(_Float16)b.y; h[6]=(_Float16)b.z; h[7]=(_Float16)b.w;
    *(reinterpret_cast<f16x8*>(bt16) + g) = h;
}

// ---------------------------------------------------------------------------
// K1: W = beta0 @ bt16^T; E = f16(exp(W)) -> first 1024 B of out rows; colsums.
// 256x256, BK=64, 16 K-tiles, 4 phases/tile.
// Gate placement rule (R13 post-mortem): per-wave counted drain must be
// FOLLOWED by a barrier BEFORE any dependent LDS read. All gates sit at the
// END of a phase, between MM and the trailing SBAR.
// Ledger @ end-P4(t): outstanding = B0(t+1):2 [P1] + B1(t+1):2 [P2] + A(t+2):8
// [P4] = 12 -> WVM8 retires both B halves, keeps A(t+2) in flight.
// t=14: A(16) not issued -> WVM0. t=15: WVM0.
// A path: f32 regs loaded @P4 (2 tiles early), cvt+ds_write @P3 (1 tile early;
// compiler reg-wait on rA retires A(t+1) exactly, order-robust).
// ---------------------------------------------------------------------------
__global__ __launch_bounds__(512) void gemm1_kernel(
    const float* __restrict__ beta0, const u16* __restrict__ bt16,
    u16* __restrict__ Eg, float* __restrict__ sg)
{
    __shared__ char lds[131072];   // 2 bufs x {A 32K, B 32K}

    const int tid  = threadIdx.x;
    const int lane = tid & 63;
    const int wid  = tid >> 6;
    const int wr = wid >> 2, wc = wid & 3;
    const int lr = lane & 15, lk = lane >> 4;
    const int srow8  = lane >> 3;
    const int schunk = ((lane & 7) ^ srow8) * 8;

    const int bid   = xcd_swz(blockIdx.x, gridDim.x);
    const int tile  = bid >> 1;
    const int chunk = bid & 1;
    const int v0 = tile * 256, t0 = chunk * 256;

    const int arow = tid >> 1, ahalf = tid & 1;
    const float* aBase = beta0 + (size_t)(v0 + arow) * EMB + ahalf * 32;

    f32x4 acc[8][4] = {};
    f16x8 af[8], bf[4];
    float4 rEv[8], rOd[8];

#define G1_LOADA(R, KT) { const float4* gp = (const float4*)(aBase + (KT) * 64); \
    _Pragma("unroll") for (int j = 0; j < 8; ++j) R[j] = gp[j]; }
#define G1_CVT(R, KT1) { char* dA = lds + ((KT1) & 1) * 65536; \
    _Pragma("unroll") for (int jj = 0; jj < 4; ++jj) { \
        float4 x = R[jj*2], y = R[jj*2+1]; \
        f16x8 h; \
        h[0]=(_Float16)x.x; h[1]=(_Float16)x.y; h[2]=(_Float16)x.z; h[3]=(_Float16)x.w; \
        h[4]=(_Float16)y.x; h[5]=(_Float16)y.y; h[6]=(_Float16)y.z; h[7]=(_Float16)y.w; \
        *(f16x8*)(dA + swz(arow, ahalf * 64 + jj * 16)) = h; } }

    auto stageB = [&](int kt, int h) {   // STRIPED: rows s*64 + h*32 + 0..31
        char* dst = lds + (kt & 1) * 65536 + 32768;
        #pragma unroll
        for (int g = 0; g < 2; ++g) {
            const int rbase = (g * 2 + (wid >> 2)) * 64 + h * 32 + (wid & 3) * 8;
            GLDS(bt16 + (size_t)(t0 + rbase + srow8) * EMB + kt * 64 + schunk,
                 dst + rbase * ROWB);
        }
    };

    // Prologue: B(0) staged; cvt(0)'s reg-wait retires A(0) AND B(0) (oldest);
    // A(1) left in flight.
    stageB(0, 0); stageB(0, 1);
    G1_LOADA(rEv, 0);
    G1_CVT(rEv, 0);
    WLG0();
    G1_LOADA(rOd, 1);
    SBAR();

#define G1_TILE(T, RC, RI) { \
    const bool st = (T) + 1 < 16; \
    char* buf = lds + ((T) & 1) * 65536; \
    /* P1 */ \
    RD_AF(buf, 0); RD_BF(buf, 0); \
    if (st) stageB((T) + 1, 0); \
    SBAR(); WLG0(); MM(0, 0); SBAR(); \
    /* P2 */ \
    RD_BF(buf, 1); \
    if (st) stageB((T) + 1, 1); \
    SBAR(); WLG0(); MM(0, 1); SBAR(); \
    /* P3: cvt A(T+1) into buf^1 (WAR vs reads of T-1: >=2 barriers back) */ \
    RD_AF(buf, 1); RD_BF(buf, 0); \
    if (st) G1_CVT(RC, (T) + 1); \
    SBAR(); WLG0(); MM(1, 0); SBAR(); \
    /* P4: issue A(T+2); gate BEFORE trailing barrier */ \
    RD_BF(buf, 1); \
    if ((T) + 2 < 16) G1_LOADA(RI, (T) + 2); \
    SBAR(); WLG0(); MM(1, 1); \
    if ((T) + 2 < 16) { WVM8(); } else { WVM0(); } \
    SBAR(); }

    for (int tt = 0; tt < 8; ++tt) {
        const int t = tt * 2;
        G1_TILE(t,     rOd, rEv);
        G1_TILE(t + 1, rEv, rOd);
    }

    // Epilogue (proven R11): 4 chunks of 64 rows; exp -> repack -> E + colsum
    __syncthreads();
    u16* ldsE = reinterpret_cast<u16*>(lds);
    float csum = 0.f;
    #pragma unroll
    for (int c = 0; c < 4; ++c) {
        if (wr == (c >> 1)) {
            const int mb = (c & 1) * 4;
            #pragma unroll
            for (int m = 0; m < 4; ++m)
              #pragma unroll
              for (int n = 0; n < 4; ++n)
                #pragma unroll
                for (int r = 0; r < 4; ++r) {
                    const int row = m * 16 + lk * 4 + r;
                    const int col = wc * 64 + n * 16 + lr;
                    H2U cv; cv.h = (_Float16)__expf(acc[mb + m][n][r]);
                    ldsE[row * 264 + col] = cv.u;
                }
        }
        __syncthreads();
        {
            const int row8 = tid >> 3, seg = tid & 7;
            const int4* sp = reinterpret_cast<const int4*>(&ldsE[row8 * 264 + seg * 32]);
            u16* dst = Eg + (size_t)(v0 + c * 64 + row8) * 2048 + t0 + seg * 32;
            int4 a0 = sp[0], a1 = sp[1], a2 = sp[2], a3 = sp[3];
            int4* dp = reinterpret_cast<int4*>(dst);
            dp[0] = a0; dp[1] = a1; dp[2] = a2; dp[3] = a3;
        }
        if (tid < 256) {
            float s = 0.f;
            for (int r = 0; r < 64; ++r) { H2U cv; cv.u = ldsE[r * 264 + tid]; s += (float)cv.h; }
            csum += s;
        }
        __syncthreads();
    }
    if (tid < 256) atomicAdd(sg + t0 + tid, csum);
}

// ---------------------------------------------------------------------------
// K2: xsT[b][t] = f16( x[t][b] * 65536 / s[t] )
// ---------------------------------------------------------------------------
__global__ void xst_kernel(const float* __restrict__ x, const float* __restrict__ s,
                           u16* __restrict__ xsT)
{
    __shared__ float tile[32][33];
    const int b0 = blockIdx.x * 32, t0 = blockIdx.y * 32;
    const int tx = threadIdx.x, ty = threadIdx.y;
    tile[ty][tx] = x[(size_t)(t0 + ty) * BATCH + b0 + tx];
    __syncthreads();
    const float sc = 65536.0f / s[t0 + tx];
    H2U cv; cv.h = (_Float16)(tile[tx][ty] * sc);
    xsT[(size_t)(b0 + ty) * TOPIC + t0 + tx] = cv.u;
}

// ---------------------------------------------------------------------------
// K3: out = (E @ xsT^T) * 2^-16. 256x256, BK=64, 8 K-tiles, 4 phases/tile.
// Stages for t+1: A0@P1, A1@P2, B0@P3, B1@P4 (B striped to match RD_BF).
// Gates (end-of-phase, before trailing SBAR):
//   end-P1: WVM2 -> retires B1(t) [needed P2], keeps A0(t+1).
//   end-P4: WVM2 -> retires A0,A1,B0 of t+1 [needed P1'], keeps B1(t+1).
// Last tile: WVM0. Dispatch 1: col-chunks 1..3; dispatch 2: chunk 0 (bytes
// ARE E; all E reads drained before any out store via final WVM0+SBAR).
// ---------------------------------------------------------------------------
__global__ __launch_bounds__(512) void gemm2_kernel(
    const u16* __restrict__ Eg, const u16* __restrict__ xsT,
    float* __restrict__ out, int c0, int nch)
{
    __shared__ char lds[131072];

    const int tid  = threadIdx.x;
    const int lane = tid & 63;
    const int wid  = tid >> 6;
    const int wr = wid >> 2, wc = wid & 3;
    const int lr = lane & 15, lk = lane >> 4;
    const int srow8  = lane >> 3;
    const int schunk = ((lane & 7) ^ srow8) * 8;

    const int bid   = xcd_swz(blockIdx.x, gridDim.x);
    const int tile  = bid / nch;
    const int chunk = bid % nch;
    const int v0 = tile * 256, b0 = (c0 + chunk) * 256;

    f32x4 acc[8][4] = {};
    f16x8 af[8], bf[4];

    auto stageA = [&](int kt, int h) {   // contiguous halves
        char* dst = lds + (kt & 1) * 65536;
        #pragma unroll
        for (int g = 0; g < 2; ++g) {
            const int rbase = h * 128 + g * 64 + wid * 8;
            GLDS(Eg + (size_t)(v0 + rbase + srow8) * 2048 + kt * 64 + schunk,
                 dst + rbase * ROWB);
        }
    };
    auto stageB = [&](int kt, int h) {   // STRIPED: rows s*64 + h*32 + 0..31
        char* dst = lds + (kt & 1) * 65536 + 32768;
        #pragma unroll
        for (int g = 0; g < 2; ++g) {
            const int rbase = (g * 2 + (wid >> 2)) * 64 + h * 32 + (wid & 3) * 8;
            GLDS(xsT + (size_t)(b0 + rbase + srow8) * TOPIC + kt * 64 + schunk,
                 dst + rbase * ROWB);
        }
    };

    stageA(0, 0); stageA(0, 1); stageB(0, 0); stageB(0, 1);
    WVM0();
    SBAR();

    for (int t = 0; t < 8; ++t) {
        const bool st = (t + 1) < 8;
        char* buf = lds + (t & 1) * 65536;
        // P1
        RD_AF(buf, 0); RD_BF(buf, 0);
        if (st) stageA(t + 1, 0);
        SBAR(); WLG0(); MM(0, 0);
        if (st) { WVM2(); } else { WVM0(); }
        SBAR();
        // P2
        RD_BF(buf, 1);
        if (st) stageA(t + 1, 1);
        SBAR(); WLG0(); MM(0, 1); SBAR();
        // P3
        RD_AF(buf, 1); RD_BF(buf, 0);
        if (st) stageB(t + 1, 0);
        SBAR(); WLG0(); MM(1, 0); SBAR();
        // P4
        RD_BF(buf, 1);
        if (st) stageB(t + 1, 1);
        SBAR(); WLG0(); MM(1, 1);
        if (st) { WVM2(); } else { WVM0(); }
        SBAR();
    }

    #pragma unroll
    for (int mh = 0; mh < 2; ++mh)
      #pragma unroll
      for (int m = 0; m < 4; ++m)
        #pragma unroll
        for (int n = 0; n < 4; ++n)
          #pragma unroll
          for (int r = 0; r < 4; ++r) {
              const int row = wr * 128 + mh * 64 + m * 16 + lk * 4 + r;
              const int col = wc * 64 + n * 16 + lr;
              out[(size_t)(v0 + row) * BATCH + b0 + col] = acc[mh * 4 + m][n][r] * 0x1p-16f;
          }
}

// ---------------------------------------------------------------------------
extern "C" void kernel_launch(void* const* d_in, const int* in_sizes, int n_in,
                              void* d_out, int out_size, void* d_ws, size_t ws_size,
                              hipStream_t stream)
{
    const float* x     = (const float*)d_in[0];
    const float* beta0 = (const float*)d_in[1];
    const float* betat = (const float*)d_in[2];
    float* out = (float*)d_out;

    const size_t need_min = 4096 + (size_t)BATCH * TOPIC * 2;   // ~1.05 MB (proven)
    if (ws_size < need_min) return;
    float* s_g  = (float*)d_ws;
    u16*   buf1 = (u16*)((char*)d_ws + 4096);

    hipMemsetAsync(d_ws, 0, 2048, stream);
    cvt_betat_kernel<<<256, 256, 0, stream>>>(betat, buf1);

    // E[v][t] lives in the first 1024 B of out row v (stride 4096 B)
    u16* EgO = (u16*)d_out;
    gemm1_kernel<<<1000, 512, 0, stream>>>(beta0, buf1, EgO, s_g);

    xst_kernel<<<dim3(BATCH / 32, TOPIC / 32), dim3(32, 32), 0, stream>>>(x, s_g, buf1);

    gemm2_kernel<<<1500, 512, 0, stream>>>(EgO, buf1, out, 1, 3);  // cols 256..1023
    gemm2_kernel<<<500,  512, 0, stream>>>(EgO, buf1, out, 0, 1);  // cols 0..255 (E bytes)
}